// Round 6
// baseline (200.548 us; speedup 1.0000x reference)
//
#include <hip/hip_runtime.h>
#include <math.h>

#define BB 4
#define LQ 2048
#define LK 2048
#define HD 8
#define VD 64
#define HV 512
#define SP 72   // padded LDS row stride (bf16 elems): 144 B, 16B-aligned

// sqrt(log2(e)) — scaling coords by this/ls makes exp(-d^2/ls^2) == exp2(-d_scaled^2)
#define COORD_SCALE 1.2011224087864498f

typedef __attribute__((ext_vector_type(8))) short bf16x8;
typedef __attribute__((ext_vector_type(4))) float f32x4;

static __device__ __forceinline__ unsigned short f2bf(float f) {  // RNE
    unsigned u = __builtin_bit_cast(unsigned, f);
    unsigned r = (u + 0x7fffu + ((u >> 16) & 1u)) >> 16;
    return (unsigned short)r;
}

static __device__ __forceinline__ float fast_exp2(float x) {
#if __has_builtin(__builtin_amdgcn_exp2f)
    return __builtin_amdgcn_exp2f(x);
#else
    return __expf(x * 0.69314718f);
#endif
}

// pack hi16(even), hi16(odd) -> one dword (bf16 truncation x2, 1 VALU op)
static __device__ __forceinline__ unsigned pack_trunc(float even, float odd) {
    return __builtin_amdgcn_perm(__builtin_bit_cast(unsigned, odd),
                                 __builtin_bit_cast(unsigned, even), 0x07060302u);
}

// ---------------- values fp32 [b][k][h][v] -> bf16 [b][h][v][k] ----------------
__global__ __launch_bounds__(256) void cvt_vals(
    const float* __restrict__ vals, unsigned short* __restrict__ vals_t)
{
    __shared__ unsigned short st[64 * SP];   // [v][k] tile
    const int tid = threadIdx.x;
    const int kt = blockIdx.x, h = blockIdx.y, b = blockIdx.z;

    const int k  = tid >> 2;
    const int vb = (tid & 3) * 16;
    const float* src = vals + (((size_t)(b * LK + kt * 64 + k) * HD + h)) * VD + vb;
    float4 f0 = *(const float4*)(src);
    float4 f1 = *(const float4*)(src + 4);
    float4 f2 = *(const float4*)(src + 8);
    float4 f3 = *(const float4*)(src + 12);
    const float fv[16] = {f0.x,f0.y,f0.z,f0.w, f1.x,f1.y,f1.z,f1.w,
                          f2.x,f2.y,f2.z,f2.w, f3.x,f3.y,f3.z,f3.w};
#pragma unroll
    for (int j = 0; j < 16; ++j) st[(vb + j) * SP + k] = f2bf(fv[j]);
    __syncthreads();

    const int v  = tid >> 2;
    const int kb = (tid & 3) * 16;
    uint4 o0 = *(const uint4*)&st[v * SP + kb];
    uint4 o1 = *(const uint4*)&st[v * SP + kb + 8];
    unsigned short* dst = vals_t + ((size_t)((b * HD + h) * VD + v)) * LK + kt * 64 + kb;
    *(uint4*)dst       = o0;
    *(uint4*)(dst + 8) = o1;
}

// ---------------- W fp32 [512][512] -> bf16 ----------------
__global__ __launch_bounds__(256) void cvt_w(
    const float* __restrict__ w, unsigned short* __restrict__ wb)
{
    const int i = (blockIdx.x * 256 + threadIdx.x) * 4;
    float4 f = *(const float4*)(w + i);
    ushort4 o;
    o.x = f2bf(f.x); o.y = f2bf(f.y); o.z = f2bf(f.z); o.w = f2bf(f.w);
    *(ushort4*)(wb + i) = o;
}

// ---------------- bake per-head scaled + masked k positions ----------------
// kposm[h][b*LK+k][3] = kpos * (sqrt(log2e)/ls_h); masked keys get x=1e38 -> score 0
__global__ __launch_bounds__(256) void bake_kpos(
    const float* __restrict__ kpos, const int* __restrict__ kmask,
    const float* __restrict__ ls, float* __restrict__ kposm)
{
    const int i = blockIdx.x * 256 + threadIdx.x;   // over HD * BB*LK
    const int h = i >> 13, bk = i & 8191;
    const float s = COORD_SCALE / ls[h];
    float x = kpos[3 * bk] * s, y = kpos[3 * bk + 1] * s, z = kpos[3 * bk + 2] * s;
    if (kmask[bk]) x = 1.0e38f;   // dx^2 -> inf -> exp2(-inf) = 0
    float* d = kposm + ((size_t)h * BB * LK + bk) * 3;
    d[0] = x; d[1] = y; d[2] = z;
}

// ---------------- fused gaussian attention: no LDS, register-pipelined ----------------
// grid 512 blocks, 256 thr. xcd=bi&7, sub=(bi>>3)&3, qc=bi>>5; slice=xcd*4+sub -> (b,h).
// wave: 32 q (2 strips) x 1 head; 2-deep register double-buffer on B-frags + k-coords.
__global__ __launch_bounds__(256) void attend5(
    const float* __restrict__ qpos,
    const float* __restrict__ kposm,
    const unsigned short* __restrict__ vals_t,
    const float* __restrict__ ls,
    unsigned short* __restrict__ attended)
{
    const int tid = threadIdx.x;
    const int bi  = blockIdx.x;
    const int xcd = bi & 7, sub = (bi >> 3) & 3, qc = bi >> 5;
    const int slice = xcd * 4 + sub;
    const int b = slice >> 3, h = slice & 7;
    const int wave = tid >> 6, lane = tid & 63;
    const int ln = lane & 15, kq = lane >> 4;

    const float sh = COORD_SCALE / ls[h];   // same scale as bake

    const int qbase = qc * 128 + wave * 32;
    float qx[2], qy[2], qz[2];
#pragma unroll
    for (int st = 0; st < 2; ++st) {
        const float* qp = qpos + (size_t)(b * LQ + qbase + st * 16 + ln) * 3;
        qx[st] = qp[0] * sh; qy[st] = qp[1] * sh; qz[st] = qp[2] * sh;
    }

    // per-lane streaming pointers
    const unsigned short* vbase = vals_t + (size_t)((b * HD + h) * VD) * LK;
    const uint4* pB[4];
#pragma unroll
    for (int vt = 0; vt < 4; ++vt)
        pB[vt] = (const uint4*)(vbase + (size_t)(vt * 16 + ln) * LK + kq * 8);
    const float4* pC = (const float4*)(kposm + ((size_t)h * BB * LK + (size_t)b * LK + kq * 8) * 3);

    // double-buffered tiles
    uint4  bB[2][8];
    float4 bC[2][12];   // [0..5] = half0 (24 floats), [6..11] = half1

    // prologue: tile 0 -> buf 0
#pragma unroll
    for (int vt = 0; vt < 4; ++vt) { bB[0][2*vt] = pB[vt][0]; bB[0][2*vt+1] = pB[vt][4]; pB[vt] += 8; }
#pragma unroll
    for (int j = 0; j < 6; ++j) { bC[0][j] = pC[j]; bC[0][6+j] = pC[24+j]; }
    pC += 48;

    f32x4 acc[2][4];
#pragma unroll
    for (int i = 0; i < 2; ++i)
#pragma unroll
        for (int j = 0; j < 4; ++j) acc[i][j] = (f32x4){0.f, 0.f, 0.f, 0.f};
    float pden[2] = {0.f, 0.f};

#pragma unroll 2
    for (int t = 0; t < 32; ++t) {
        const int cur = t & 1, nxt = cur ^ 1;

        // ---- issue next tile's loads first (latency hidden under compute) ----
        if (t < 31) {
#pragma unroll
            for (int vt = 0; vt < 4; ++vt) {
                bB[nxt][2*vt]   = pB[vt][0];
                bB[nxt][2*vt+1] = pB[vt][4];
                pB[vt] += 8;
            }
#pragma unroll
            for (int j = 0; j < 6; ++j) { bC[nxt][j] = pC[j]; bC[nxt][6+j] = pC[24+j]; }
            pC += 48;
        }

        // ---- scores from registers (A-frag layout), then MFMA ----
        const float* kcf = (const float*)&bC[cur][0];
        bf16x8 afr[2][2];
#pragma unroll
        for (int half = 0; half < 2; ++half) {
            const float* kc = kcf + half * 24;
#pragma unroll
            for (int st = 0; st < 2; ++st) {
                float s[8];
#pragma unroll
                for (int j = 0; j < 8; ++j) {
                    const float dx = qx[st] - kc[3 * j];
                    const float dy = qy[st] - kc[3 * j + 1];
                    const float dz = qz[st] - kc[3 * j + 2];
                    const float d2 = fmaf(dx, dx, fmaf(dy, dy, dz * dz));
                    const float sc = fast_exp2(-d2);   // neg is free input modifier
                    pden[st] += sc;
                    s[j] = sc;
                }
                unsigned pk[4];
#pragma unroll
                for (int p = 0; p < 4; ++p) pk[p] = pack_trunc(s[2 * p], s[2 * p + 1]);
                afr[st][half] = __builtin_bit_cast(bf16x8, *(uint4*)pk);
            }
        }

#pragma unroll
        for (int st = 0; st < 2; ++st)
#pragma unroll
            for (int vt = 0; vt < 4; ++vt) {
                const bf16x8 b0 = __builtin_bit_cast(bf16x8, *(uint4*)&bB[cur][2*vt]);
                const bf16x8 b1 = __builtin_bit_cast(bf16x8, *(uint4*)&bB[cur][2*vt+1]);
                acc[st][vt] = __builtin_amdgcn_mfma_f32_16x16x32_bf16(afr[st][0], b0, acc[st][vt], 0, 0, 0);
                acc[st][vt] = __builtin_amdgcn_mfma_f32_16x16x32_bf16(afr[st][1], b1, acc[st][vt], 0, 0, 0);
            }
    }

    // ---- denominator: reduce over kq groups, redistribute to C-layout rows ----
    float inv[2];
#pragma unroll
    for (int st = 0; st < 2; ++st) {
        float v = pden[st];
        v += __shfl_xor(v, 16, 64);
        v += __shfl_xor(v, 32, 64);
        inv[st] = 1.0f / (v + 1e-5f);          // valid for q = st*16 + ln
    }
    float ivq[2][4];
#pragma unroll
    for (int st = 0; st < 2; ++st)
#pragma unroll
        for (int r = 0; r < 4; ++r) ivq[st][r] = __shfl(inv[st], kq * 4 + r, 64);

#pragma unroll
    for (int st = 0; st < 2; ++st)
#pragma unroll
        for (int vt = 0; vt < 4; ++vt)
#pragma unroll
            for (int r = 0; r < 4; ++r) {
                const int q = qbase + st * 16 + kq * 4 + r;
                attended[(size_t)(b * LQ + q) * HV + h * VD + vt * 16 + ln] =
                    f2bf(acc[st][vt][r] * ivq[st][r]);
            }
}

// ---------------- projection: C[8192][512] = A_bf16 @ Wb^T, 64x64 tiles ----------------
__global__ __launch_bounds__(256, 4) void proj5(
    const unsigned short* __restrict__ A,
    const unsigned short* __restrict__ Wb,
    float* __restrict__ C)
{
    __shared__ __align__(16) unsigned short sA[64 * SP];
    __shared__ __align__(16) unsigned short sW[64 * SP];

    const int tid = threadIdx.x;
    const int n0 = blockIdx.x * 64, m0 = blockIdx.y * 64;
    const int wave = tid >> 6, lane = tid & 63;
    const int ln = lane & 15, kq = lane >> 4;
    const int mw = (wave >> 1) * 32, nw = (wave & 1) * 32;
    const int srow = tid >> 2, skb = (tid & 3) * 16;

    f32x4 acc[2][2];
#pragma unroll
    for (int i = 0; i < 2; ++i)
#pragma unroll
        for (int j = 0; j < 2; ++j) acc[i][j] = (f32x4){0.f, 0.f, 0.f, 0.f};

    for (int k0 = 0; k0 < 512; k0 += 64) {
        __syncthreads();
        {
            const unsigned short* a = A  + (size_t)(m0 + srow) * 512 + k0 + skb;
            const unsigned short* w = Wb + (size_t)(n0 + srow) * 512 + k0 + skb;
            uint4 a0 = ((const uint4*)a)[0], a1 = ((const uint4*)a)[1];
            uint4 w0 = ((const uint4*)w)[0], w1 = ((const uint4*)w)[1];
            unsigned short* da = &sA[srow * SP + skb];
            unsigned short* dw = &sW[srow * SP + skb];
            ((uint4*)da)[0] = a0; ((uint4*)da)[1] = a1;
            ((uint4*)dw)[0] = w0; ((uint4*)dw)[1] = w1;
        }
        __syncthreads();

        bf16x8 af[2][2], bfr[2][2];
#pragma unroll
        for (int mt = 0; mt < 2; ++mt) {
            const unsigned short* ap = &sA[(mw + mt * 16 + ln) * SP + kq * 8];
            af[mt][0] = *(const bf16x8*)(ap);
            af[mt][1] = *(const bf16x8*)(ap + 32);
        }
#pragma unroll
        for (int nt = 0; nt < 2; ++nt) {
            const unsigned short* bp = &sW[(nw + nt * 16 + ln) * SP + kq * 8];
            bfr[nt][0] = *(const bf16x8*)(bp);
            bfr[nt][1] = *(const bf16x8*)(bp + 32);
        }
#pragma unroll
        for (int mt = 0; mt < 2; ++mt)
#pragma unroll
            for (int nt = 0; nt < 2; ++nt) {
                acc[mt][nt] = __builtin_amdgcn_mfma_f32_16x16x32_bf16(af[mt][0], bfr[nt][0], acc[mt][nt], 0, 0, 0);
                acc[mt][nt] = __builtin_amdgcn_mfma_f32_16x16x32_bf16(af[mt][1], bfr[nt][1], acc[mt][nt], 0, 0, 0);
            }
    }

#pragma unroll
    for (int mt = 0; mt < 2; ++mt)
#pragma unroll
        for (int nt = 0; nt < 2; ++nt)
#pragma unroll
            for (int r = 0; r < 4; ++r)
                C[(size_t)(m0 + mw + mt * 16 + kq * 4 + r) * 512 + n0 + nw + nt * 16 + ln] =
                    acc[mt][nt][r];
}

extern "C" void kernel_launch(void* const* d_in, const int* in_sizes, int n_in,
                              void* d_out, int out_size, void* d_ws, size_t ws_size,
                              hipStream_t stream) {
    const float* qpos  = (const float*)d_in[0];
    const float* kpos  = (const float*)d_in[1];
    const float* vals  = (const float*)d_in[2];
    const int*   kmask = (const int*)  d_in[3];
    const float* ls    = (const float*)d_in[4];
    const float* wout  = (const float*)d_in[5];
    float* out = (float*)d_out;

    unsigned short* vals_t   = (unsigned short*)d_ws;                    // 8 MiB
    unsigned short* attended = vals_t + (size_t)4 * 1024 * 1024;         // 8 MiB
    unsigned short* w_bf     = vals_t + (size_t)8 * 1024 * 1024;         // 0.5 MiB
    float*          kposm    = (float*)(vals_t + (size_t)8 * 1024 * 1024 + 512 * 1024); // 768 KiB

    cvt_vals <<<dim3(32, HD, BB), 256, 0, stream>>>(vals, vals_t);
    cvt_w    <<<dim3(256), 256, 0, stream>>>(wout, w_bf);
    bake_kpos<<<dim3(HD * BB * LK / 256), 256, 0, stream>>>(kpos, kmask, ls, kposm);
    attend5  <<<dim3(512), 256, 0, stream>>>(qpos, kposm, vals_t, ls, attended);
    proj5    <<<dim3(512 / 64, (BB * LQ) / 64), 256, 0, stream>>>(attended, w_bf, out);
}